// Round 4
// baseline (2008.013 us; speedup 1.0000x reference)
//
#include <hip/hip_runtime.h>

#define N_M 100000
#define N_D 30000
#define N_A 80000

// source-chunk binning: 16384 src nodes/chunk (64-wide bf16 rows -> 2.1 MB, fits 4 MB per-XCD L2)
#define CSHIFT 14
#define NC_M 7   // ceil(100000/16384)
#define NC_D 2   // ceil(30000/16384)
#define NC_A 5   // ceil(80000/16384)

// global bin layout: [md: N_D*NC_M | dm: N_M*NC_D | ma: N_A*NC_M | am: N_M*NC_A]
#define BO_MD 0
#define BO_DM (BO_MD + N_D * NC_M)   // 210000
#define BO_MA (BO_DM + N_M * NC_D)   // 410000
#define BO_AM (BO_MA + N_A * NC_M)   // 970000
#define B_TOT (BO_AM + N_M * NC_A)   // 1470000

#define SCHUNK 4096
#define NSB ((B_TOT + SCHUNK - 1) / SCHUNK)  // 359

typedef unsigned int u32;
typedef unsigned short u16;

__device__ __forceinline__ u16 f2bf(float f) {
  u32 u = __float_as_uint(f);
  return (u16)((u + 0x7FFFu + ((u >> 16) & 1u)) >> 16);
}
__device__ __forceinline__ float bf2f(u16 b) {
  return __uint_as_float(((u32)b) << 16);
}
// packed edge: src[31:15] (src<131072), bf16(ew) sans sign in [14:0] (ew>=0)
__device__ __forceinline__ u32 pack_edge(int src, float ew) {
  return ((u32)src << 15) | ((u32)f2bf(ew) & 0x7FFFu);
}
__device__ __forceinline__ float edge_w(u32 p) {
  return __uint_as_float((p & 0x7FFFu) << 16);
}

// ===========================================================================
// CSR-bin build: hist -> 3-phase scan (in-place, bins becomes cursor) -> reorder
// After reorder, bins[b] = END of bin b; with binsRaw[0]=0 sentinel,
// start(b) = binsRaw[b], end(b) = binsRaw[b+1].
// ===========================================================================
struct Rel { const int* src; const int* dst; const float* ew; int nE; int binBase; int nC; };
struct Rel4 { Rel r[4]; int blkStart[5]; };

__global__ __launch_bounds__(256) void hist_all(Rel4 P, int* __restrict__ bins) {
  int b = blockIdx.x;
  int s = 0;
  while (b >= P.blkStart[s + 1]) s++;
  const Rel R = P.r[s];
  int e = (b - P.blkStart[s]) * 256 + threadIdx.x;
  if (e < R.nE) {
    int bin = R.binBase + R.dst[e] * R.nC + (R.src[e] >> CSHIFT);
    atomicAdd(&bins[bin], 1);
  }
}

__global__ __launch_bounds__(256) void scan_p1(const int* __restrict__ c, int* __restrict__ partial) {
  int base = blockIdx.x * SCHUNK + threadIdx.x * 16;
  int s = 0;
#pragma unroll
  for (int i = 0; i < 16; i++) { int idx = base + i; if (idx < B_TOT) s += c[idx]; }
  for (int off = 32; off; off >>= 1) s += __shfl_down(s, off, 64);
  __shared__ int ws[4];
  if ((threadIdx.x & 63) == 0) ws[threadIdx.x >> 6] = s;
  __syncthreads();
  if (threadIdx.x == 0) partial[blockIdx.x] = ws[0] + ws[1] + ws[2] + ws[3];
}

__global__ __launch_bounds__(256) void scan_p2(const int* __restrict__ partial, int* __restrict__ blockOfs) {
  int t = threadIdx.x;
  int p0 = (2 * t < NSB) ? partial[2 * t] : 0;
  int p1 = (2 * t + 1 < NSB) ? partial[2 * t + 1] : 0;
  int s = p0 + p1;
  int lane = t & 63, wid = t >> 6;
  int sc = s;
#pragma unroll
  for (int off = 1; off < 64; off <<= 1) { int v = __shfl_up(sc, off, 64); if (lane >= off) sc += v; }
  __shared__ int ws[4];
  if (lane == 63) ws[wid] = sc;
  __syncthreads();
  int wexcl = 0;
  for (int w = 0; w < 4; w++) if (w < wid) wexcl += ws[w];
  int excl = wexcl + sc - s;
  if (2 * t < NSB) blockOfs[2 * t] = excl;
  if (2 * t + 1 < NSB) blockOfs[2 * t + 1] = excl + p0;
}

__global__ __launch_bounds__(256) void scan_p3(int* __restrict__ bins, const int* __restrict__ blockOfs) {
  int base = blockIdx.x * SCHUNK + threadIdx.x * 16;
  int v[16];
  int s = 0;
#pragma unroll
  for (int i = 0; i < 16; i++) { int idx = base + i; v[i] = (idx < B_TOT) ? bins[idx] : 0; s += v[i]; }
  int lane = threadIdx.x & 63, wid = threadIdx.x >> 6;
  int sc = s;
#pragma unroll
  for (int off = 1; off < 64; off <<= 1) { int t = __shfl_up(sc, off, 64); if (lane >= off) sc += t; }
  __shared__ int ws[4];
  if (lane == 63) ws[wid] = sc;
  __syncthreads();
  int wexcl = 0;
  for (int w = 0; w < 4; w++) if (w < wid) wexcl += ws[w];
  int p = blockOfs[blockIdx.x] + wexcl + (sc - s);
#pragma unroll
  for (int i = 0; i < 16; i++) { int idx = base + i; if (idx < B_TOT) bins[idx] = p; p += v[i]; }
}

__global__ __launch_bounds__(256) void reorder_all(Rel4 P, int* __restrict__ bins, u32* __restrict__ pairs) {
  int b = blockIdx.x;
  int s = 0;
  while (b >= P.blkStart[s + 1]) s++;
  const Rel R = P.r[s];
  int e = (b - P.blkStart[s]) * 256 + threadIdx.x;
  if (e < R.nE) {
    int src = R.src[e];
    int bin = R.binBase + R.dst[e] * R.nC + (src >> CSHIFT);
    int p = atomicAdd(&bins[bin], 1);
    pairs[p] = pack_edge(src, R.ew[e]);
  }
}

// ===========================================================================
// Layer-1 dense transforms: t = x @ W1_rel (bf16), r = x @ W1_root + b (bf16)
// ===========================================================================
__global__ __launch_bounds__(256) void l1_tr_m(
    const float* __restrict__ x,
    const float* __restrict__ Wr0, const float* __restrict__ Wr2,
    const float* __restrict__ Wt1, const float* __restrict__ Wt3,
    const float* __restrict__ b1a, const float* __restrict__ b1b,
    u16* __restrict__ t0, u16* __restrict__ t2, u16* __restrict__ r, int n) {
  __shared__ float A[4096], B[4096], C[4096];
  for (int i = threadIdx.x * 4; i < 4096; i += 1024) {
    *(float4*)&A[i] = *(const float4*)&Wr0[i];
    *(float4*)&B[i] = *(const float4*)&Wr2[i];
    float4 p = *(const float4*)&Wt1[i], q = *(const float4*)&Wt3[i];
    *(float4*)&C[i] = make_float4(p.x + q.x, p.y + q.y, p.z + q.z, p.w + q.w);
  }
  __syncthreads();
  int lane = threadIdx.x & 63, wid = threadIdx.x >> 6;
  int wave = blockIdx.x * 4 + wid, nW = gridDim.x * 4;
  float bj = b1a[lane] + b1b[lane];
  for (int base = wave * 4; base < n; base += nW * 4) {
    int n0 = base, n1 = min(base + 1, n - 1), n2 = min(base + 2, n - 1), n3 = min(base + 3, n - 1);
    float o0a = 0, o0b = 0, o0c = bj, o1a = 0, o1b = 0, o1c = bj;
    float o2a = 0, o2b = 0, o2c = bj, o3a = 0, o3b = 0, o3c = bj;
#pragma unroll 4
    for (int k = 0; k < 64; k++) {
      float wa = A[k * 64 + lane], wb = B[k * 64 + lane], wc = C[k * 64 + lane];
      float x0 = x[(size_t)n0 * 64 + k], x1 = x[(size_t)n1 * 64 + k];
      float x2 = x[(size_t)n2 * 64 + k], x3 = x[(size_t)n3 * 64 + k];
      o0a = fmaf(x0, wa, o0a); o0b = fmaf(x0, wb, o0b); o0c = fmaf(x0, wc, o0c);
      o1a = fmaf(x1, wa, o1a); o1b = fmaf(x1, wb, o1b); o1c = fmaf(x1, wc, o1c);
      o2a = fmaf(x2, wa, o2a); o2b = fmaf(x2, wb, o2b); o2c = fmaf(x2, wc, o2c);
      o3a = fmaf(x3, wa, o3a); o3b = fmaf(x3, wb, o3b); o3c = fmaf(x3, wc, o3c);
    }
    t0[(size_t)n0 * 64 + lane] = f2bf(o0a); t2[(size_t)n0 * 64 + lane] = f2bf(o0b); r[(size_t)n0 * 64 + lane] = f2bf(o0c);
    if (base + 1 < n) { t0[(size_t)n1 * 64 + lane] = f2bf(o1a); t2[(size_t)n1 * 64 + lane] = f2bf(o1b); r[(size_t)n1 * 64 + lane] = f2bf(o1c); }
    if (base + 2 < n) { t0[(size_t)n2 * 64 + lane] = f2bf(o2a); t2[(size_t)n2 * 64 + lane] = f2bf(o2b); r[(size_t)n2 * 64 + lane] = f2bf(o2c); }
    if (base + 3 < n) { t0[(size_t)n3 * 64 + lane] = f2bf(o3a); t2[(size_t)n3 * 64 + lane] = f2bf(o3b); r[(size_t)n3 * 64 + lane] = f2bf(o3c); }
  }
}

__global__ __launch_bounds__(256) void l1_tr_s(
    const float* __restrict__ x,
    const float* __restrict__ Wrel, const float* __restrict__ Wroot,
    const float* __restrict__ bias,
    u16* __restrict__ t, u16* __restrict__ r, int n) {
  __shared__ float A[4096], C[4096];
  for (int i = threadIdx.x * 4; i < 4096; i += 1024) {
    *(float4*)&A[i] = *(const float4*)&Wrel[i];
    *(float4*)&C[i] = *(const float4*)&Wroot[i];
  }
  __syncthreads();
  int lane = threadIdx.x & 63, wid = threadIdx.x >> 6;
  int wave = blockIdx.x * 4 + wid, nW = gridDim.x * 4;
  float bj = bias[lane];
  for (int base = wave * 4; base < n; base += nW * 4) {
    int n0 = base, n1 = min(base + 1, n - 1), n2 = min(base + 2, n - 1), n3 = min(base + 3, n - 1);
    float o0a = 0, o0c = bj, o1a = 0, o1c = bj, o2a = 0, o2c = bj, o3a = 0, o3c = bj;
#pragma unroll 4
    for (int k = 0; k < 64; k++) {
      float wa = A[k * 64 + lane], wc = C[k * 64 + lane];
      float x0 = x[(size_t)n0 * 64 + k], x1 = x[(size_t)n1 * 64 + k];
      float x2 = x[(size_t)n2 * 64 + k], x3 = x[(size_t)n3 * 64 + k];
      o0a = fmaf(x0, wa, o0a); o0c = fmaf(x0, wc, o0c);
      o1a = fmaf(x1, wa, o1a); o1c = fmaf(x1, wc, o1c);
      o2a = fmaf(x2, wa, o2a); o2c = fmaf(x2, wc, o2c);
      o3a = fmaf(x3, wa, o3a); o3c = fmaf(x3, wc, o3c);
    }
    t[(size_t)n0 * 64 + lane] = f2bf(o0a); r[(size_t)n0 * 64 + lane] = f2bf(o0c);
    if (base + 1 < n) { t[(size_t)n1 * 64 + lane] = f2bf(o1a); r[(size_t)n1 * 64 + lane] = f2bf(o1c); }
    if (base + 2 < n) { t[(size_t)n2 * 64 + lane] = f2bf(o2a); r[(size_t)n2 * 64 + lane] = f2bf(o2c); }
    if (base + 3 < n) { t[(size_t)n3 * 64 + lane] = f2bf(o3a); r[(size_t)n3 * 64 + lane] = f2bf(o3c); }
  }
}

// ===========================================================================
// Chunk-ordered gather of 64-wide rows into acc[i] (lane = feature).
// ===========================================================================
__device__ __forceinline__ float gatherbin64(
    const int* __restrict__ be, const u32* __restrict__ pairs,
    const u16* __restrict__ tbl, int b, int lane, float a) {
  int e = be[b], s1 = be[b + 1];
  for (; e + 4 <= s1; e += 4) {
    u32 p0 = pairs[e], p1 = pairs[e + 1], p2 = pairs[e + 2], p3 = pairs[e + 3];
    float v0 = bf2f(tbl[(size_t)(p0 >> 15) * 64 + lane]);
    float v1 = bf2f(tbl[(size_t)(p1 >> 15) * 64 + lane]);
    float v2 = bf2f(tbl[(size_t)(p2 >> 15) * 64 + lane]);
    float v3 = bf2f(tbl[(size_t)(p3 >> 15) * 64 + lane]);
    a += edge_w(p0) * v0 + edge_w(p1) * v1 + edge_w(p2) * v2 + edge_w(p3) * v3;
  }
  if (e + 2 <= s1) {
    u32 p0 = pairs[e], p1 = pairs[e + 1];
    a += edge_w(p0) * bf2f(tbl[(size_t)(p0 >> 15) * 64 + lane])
       + edge_w(p1) * bf2f(tbl[(size_t)(p1 >> 15) * 64 + lane]);
    e += 2;
  }
  if (e < s1) { u32 p = pairs[e]; a += edge_w(p) * bf2f(tbl[(size_t)(p >> 15) * 64 + lane]); }
  return a;
}

// Fused: L1 gather (+root, relu) + L2 transform; root/bias part of output
// written directly to d_out (f32); y table (bf16) for the L2 gather.
template<int NPW>
__global__ __launch_bounds__(256) void fused1(
    const int* __restrict__ be, const u32* __restrict__ pairs,
    const u16* __restrict__ tbl, const u16* __restrict__ r1,
    const float* __restrict__ W2r, const float* __restrict__ W2t,
    const float* __restrict__ b2s,
    u16* __restrict__ y, float* __restrict__ oroot,
    int n, int nC, int binBase) {
  __shared__ u16 Wy[2048], Wt[2048];
  __shared__ float bs[32];
  __shared__ float scr[4][64];
  for (int i = threadIdx.x; i < 2048; i += 256) { Wy[i] = f2bf(W2r[i]); Wt[i] = f2bf(W2t[i]); }
  if (threadIdx.x < 32) bs[threadIdx.x] = b2s[threadIdx.x];
  __syncthreads();
  int lane = threadIdx.x & 63, wid = threadIdx.x >> 6;
  int node0 = (blockIdx.x * 4 + wid) * NPW;
  float acc[NPW];
#pragma unroll
  for (int i = 0; i < NPW; i++) acc[i] = 0.f;
  for (int c = 0; c < nC; c++) {
#pragma unroll
    for (int i = 0; i < NPW; i++) {
      int node = node0 + i;
      if (node < n) acc[i] = gatherbin64(be, pairs, tbl, binBase + node * nC + c, lane, acc[i]);
    }
  }
  int j = lane & 31, half = lane >> 5;
#pragma unroll
  for (int i = 0; i < NPW; i++) {
    int node = node0 + i;
    if (node >= n) continue;
    float hv = fmaxf(acc[i] + bf2f(r1[(size_t)node * 64 + lane]), 0.f);
    scr[wid][lane] = hv;
    float oy = 0.f, ot = 0.f;
#pragma unroll
    for (int kk = 0; kk < 32; kk++) {
      int k = (half << 5) + kk;
      float s = scr[wid][k];
      oy = fmaf(s, bf2f(Wy[k * 32 + j]), oy);
      ot = fmaf(s, bf2f(Wt[k * 32 + j]), ot);
    }
    oy += __shfl_xor(oy, 32);
    ot += __shfl_xor(ot, 32);
    if (lane < 32) {
      y[(size_t)node * 32 + lane] = f2bf(oy);
      oroot[(size_t)node * 32 + lane] = ot + bs[lane];
    }
  }
}

// Movie variant: two incoming relations, three L2 matrices.
__global__ __launch_bounds__(256) void fusedm(
    const int* __restrict__ be, const u32* __restrict__ pairs,
    const u16* __restrict__ tbl1,   // t_dm (director rows)
    const u16* __restrict__ tbl2,   // t_am (actor rows)
    const u16* __restrict__ r1,
    const float* __restrict__ W2r0, const float* __restrict__ W2r2,
    const float* __restrict__ W2t1, const float* __restrict__ W2t3,
    const float* __restrict__ b2a, const float* __restrict__ b2b,
    u16* __restrict__ y0, u16* __restrict__ y2, float* __restrict__ oroot, int n) {
  __shared__ u16 Wy0[2048], Wy2[2048], Wt[2048];
  __shared__ float bs[32];
  __shared__ float scr[4][64];
  for (int i = threadIdx.x; i < 2048; i += 256) {
    Wy0[i] = f2bf(W2r0[i]); Wy2[i] = f2bf(W2r2[i]); Wt[i] = f2bf(W2t1[i] + W2t3[i]);
  }
  if (threadIdx.x < 32) bs[threadIdx.x] = b2a[threadIdx.x] + b2b[threadIdx.x];
  __syncthreads();
  int lane = threadIdx.x & 63, wid = threadIdx.x >> 6;
  int node0 = (blockIdx.x * 4 + wid) * 8;
  float acc[8];
#pragma unroll
  for (int i = 0; i < 8; i++) acc[i] = 0.f;
  for (int c = 0; c < NC_D; c++) {
#pragma unroll
    for (int i = 0; i < 8; i++) {
      int node = node0 + i;
      if (node < n) acc[i] = gatherbin64(be, pairs, tbl1, BO_DM + node * NC_D + c, lane, acc[i]);
    }
  }
  for (int c = 0; c < NC_A; c++) {
#pragma unroll
    for (int i = 0; i < 8; i++) {
      int node = node0 + i;
      if (node < n) acc[i] = gatherbin64(be, pairs, tbl2, BO_AM + node * NC_A + c, lane, acc[i]);
    }
  }
  int j = lane & 31, half = lane >> 5;
#pragma unroll
  for (int i = 0; i < 8; i++) {
    int node = node0 + i;
    if (node >= n) continue;
    float hv = fmaxf(acc[i] + bf2f(r1[(size_t)node * 64 + lane]), 0.f);
    scr[wid][lane] = hv;
    float o0 = 0.f, o2 = 0.f, ot = 0.f;
#pragma unroll
    for (int kk = 0; kk < 32; kk++) {
      int k = (half << 5) + kk;
      float s = scr[wid][k];
      o0 = fmaf(s, bf2f(Wy0[k * 32 + j]), o0);
      o2 = fmaf(s, bf2f(Wy2[k * 32 + j]), o2);
      ot = fmaf(s, bf2f(Wt[k * 32 + j]), ot);
    }
    o0 += __shfl_xor(o0, 32);
    o2 += __shfl_xor(o2, 32);
    ot += __shfl_xor(ot, 32);
    if (lane < 32) {
      y0[(size_t)node * 32 + lane] = f2bf(o0);
      y2[(size_t)node * 32 + lane] = f2bf(o2);
      oroot[(size_t)node * 32 + lane] = ot + bs[lane];
    }
  }
}

// ===========================================================================
// Layer-2 gather (32-wide rows, half-wave edge split), accumulating onto the
// root/bias values fused1/fusedm already wrote to d_out.
// ===========================================================================
__device__ __forceinline__ float gatherbin32(
    const int* __restrict__ be, const u32* __restrict__ pairs,
    const u16* __restrict__ ytbl, int b, int j, int half, float a) {
  int e = be[b] + half, s1 = be[b + 1];
  for (; e + 6 < s1; e += 8) {
    u32 p0 = pairs[e], p1 = pairs[e + 2], p2 = pairs[e + 4], p3 = pairs[e + 6];
    a += edge_w(p0) * bf2f(ytbl[(size_t)(p0 >> 15) * 32 + j])
       + edge_w(p1) * bf2f(ytbl[(size_t)(p1 >> 15) * 32 + j])
       + edge_w(p2) * bf2f(ytbl[(size_t)(p2 >> 15) * 32 + j])
       + edge_w(p3) * bf2f(ytbl[(size_t)(p3 >> 15) * 32 + j]);
  }
  for (; e < s1; e += 2) {
    u32 p = pairs[e];
    a += edge_w(p) * bf2f(ytbl[(size_t)(p >> 15) * 32 + j]);
  }
  return a;
}

template<int NPW>
__global__ __launch_bounds__(256) void out1(
    const int* __restrict__ be, const u32* __restrict__ pairs,
    const u16* __restrict__ ytbl, float* __restrict__ out,
    int n, int nC, int binBase) {
  int lane = threadIdx.x & 63, wid = threadIdx.x >> 6;
  int node0 = (blockIdx.x * 4 + wid) * NPW;
  int j = lane & 31, half = lane >> 5;
  float acc[NPW];
#pragma unroll
  for (int i = 0; i < NPW; i++) acc[i] = 0.f;
  for (int c = 0; c < nC; c++) {
#pragma unroll
    for (int i = 0; i < NPW; i++) {
      int node = node0 + i;
      if (node < n) acc[i] = gatherbin32(be, pairs, ytbl, binBase + node * nC + c, j, half, acc[i]);
    }
  }
#pragma unroll
  for (int i = 0; i < NPW; i++) {
    int node = node0 + i;
    if (node >= n) continue;
    float o = acc[i] + __shfl_xor(acc[i], 32);
    if (lane < 32) out[(size_t)node * 32 + lane] += o;
  }
}

__global__ __launch_bounds__(256) void outm(
    const int* __restrict__ be, const u32* __restrict__ pairs,
    const u16* __restrict__ y1,   // y_dm (director rows)
    const u16* __restrict__ y2,   // y_am (actor rows)
    float* __restrict__ out, int n) {
  int lane = threadIdx.x & 63, wid = threadIdx.x >> 6;
  int node0 = (blockIdx.x * 4 + wid) * 8;
  int j = lane & 31, half = lane >> 5;
  float acc[8];
#pragma unroll
  for (int i = 0; i < 8; i++) acc[i] = 0.f;
  for (int c = 0; c < NC_D; c++) {
#pragma unroll
    for (int i = 0; i < 8; i++) {
      int node = node0 + i;
      if (node < n) acc[i] = gatherbin32(be, pairs, y1, BO_DM + node * NC_D + c, j, half, acc[i]);
    }
  }
  for (int c = 0; c < NC_A; c++) {
#pragma unroll
    for (int i = 0; i < 8; i++) {
      int node = node0 + i;
      if (node < n) acc[i] = gatherbin32(be, pairs, y2, BO_AM + node * NC_A + c, j, half, acc[i]);
    }
  }
#pragma unroll
  for (int i = 0; i < 8; i++) {
    int node = node0 + i;
    if (node >= n) continue;
    float o = acc[i] + __shfl_xor(acc[i], 32);
    if (lane < 32) out[(size_t)node * 32 + lane] += o;
  }
}

static inline int nblk(long long threads) { return (int)((threads + 255) / 256); }

extern "C" void kernel_launch(void* const* d_in, const int* in_sizes, int n_in,
                              void* d_out, int out_size, void* d_ws, size_t ws_size,
                              hipStream_t stream) {
  const float* x_m = (const float*)d_in[0];
  const float* x_d = (const float*)d_in[1];
  const float* x_a = (const float*)d_in[2];
  const int* src_md = (const int*)d_in[3];
  const int* dst_md = (const int*)d_in[4];
  const float* ew_md = (const float*)d_in[5];
  const int* src_dm = (const int*)d_in[6];
  const int* dst_dm = (const int*)d_in[7];
  const float* ew_dm = (const float*)d_in[8];
  const int* src_ma = (const int*)d_in[9];
  const int* dst_ma = (const int*)d_in[10];
  const float* ew_ma = (const float*)d_in[11];
  const int* src_am = (const int*)d_in[12];
  const int* dst_am = (const int*)d_in[13];
  const float* ew_am = (const float*)d_in[14];
  const float* W1_rel = (const float*)d_in[15];
  const float* b1 = (const float*)d_in[16];
  const float* W1_root = (const float*)d_in[17];
  const float* W2_rel = (const float*)d_in[18];
  const float* b2 = (const float*)d_in[19];
  const float* W2_root = (const float*)d_in[20];

  const int E_md = in_sizes[3];
  const int E_dm = in_sizes[6];
  const int E_ma = in_sizes[9];
  const int E_am = in_sizes[12];
  const long long E_tot = (long long)E_md + E_dm + E_ma + E_am;

  // ---- workspace ----
  char* w = (char*)d_ws;
  int* binsRaw = (int*)w;   w += (size_t)(B_TOT + 1) * 4;  // [0]=0 sentinel; +1 = counts/cursor
  int* blockOfs = (int*)w;  w += (size_t)NSB * 4;
  u32* pairs = (u32*)w;     w += (size_t)E_tot * 4;
  u16* t_md = (u16*)w;      w += (size_t)N_M * 64 * 2;
  u16* t_dm = (u16*)w;      w += (size_t)N_D * 64 * 2;
  u16* t_ma = (u16*)w;      w += (size_t)N_M * 64 * 2;
  u16* t_am = (u16*)w;      w += (size_t)N_A * 64 * 2;
  u16* r_m  = (u16*)w;      w += (size_t)N_M * 64 * 2;
  u16* r_d  = (u16*)w;      w += (size_t)N_D * 64 * 2;
  u16* r_a  = (u16*)w;      w += (size_t)N_A * 64 * 2;
  u16* y_md = (u16*)w;      w += (size_t)N_M * 32 * 2;
  u16* y_dm = (u16*)w;      w += (size_t)N_D * 32 * 2;
  u16* y_ma = (u16*)w;      w += (size_t)N_M * 32 * 2;
  u16* y_am = (u16*)w;      w += (size_t)N_A * 32 * 2;
  if ((size_t)(w - (char*)d_ws) > ws_size) return;
  int* bins = binsRaw + 1;

  float* o_m = (float*)d_out;
  float* o_d = o_m + (size_t)N_M * 32;
  float* o_a = o_d + (size_t)N_D * 32;

  // ---- CSR-bin build ----
  hipMemsetAsync(binsRaw, 0, (size_t)(B_TOT + 1) * 4, stream);

  Rel4 P;
  P.r[0] = { src_md, dst_md, ew_md, E_md, BO_MD, NC_M };
  P.r[1] = { src_dm, dst_dm, ew_dm, E_dm, BO_DM, NC_D };
  P.r[2] = { src_ma, dst_ma, ew_ma, E_ma, BO_MA, NC_M };
  P.r[3] = { src_am, dst_am, ew_am, E_am, BO_AM, NC_A };
  P.blkStart[0] = 0;
  P.blkStart[1] = P.blkStart[0] + nblk(E_md);
  P.blkStart[2] = P.blkStart[1] + nblk(E_dm);
  P.blkStart[3] = P.blkStart[2] + nblk(E_ma);
  P.blkStart[4] = P.blkStart[3] + nblk(E_am);

  hist_all<<<P.blkStart[4], 256, 0, stream>>>(P, bins);
  scan_p1<<<NSB, 256, 0, stream>>>(bins, blockOfs /*reuse as partial*/);
  scan_p2<<<1, 256, 0, stream>>>(blockOfs, blockOfs);
  scan_p3<<<NSB, 256, 0, stream>>>(bins, blockOfs);
  reorder_all<<<P.blkStart[4], 256, 0, stream>>>(P, bins, pairs);

  // ---- layer-1 dense transforms ----
  l1_tr_m<<<768, 256, 0, stream>>>(x_m, W1_rel + 0 * 4096, W1_rel + 2 * 4096,
                                   W1_root + 1 * 4096, W1_root + 3 * 4096,
                                   b1 + 1 * 64, b1 + 3 * 64, t_md, t_ma, r_m, N_M);
  l1_tr_s<<<512, 256, 0, stream>>>(x_d, W1_rel + 1 * 4096, W1_root + 0 * 4096,
                                   b1 + 0 * 64, t_dm, r_d, N_D);
  l1_tr_s<<<512, 256, 0, stream>>>(x_a, W1_rel + 3 * 4096, W1_root + 2 * 4096,
                                   b1 + 2 * 64, t_am, r_a, N_A);

  // ---- fused L1-gather + L2-transform (writes root part to d_out) ----
  fused1<4><<<(N_D + 15) / 16, 256, 0, stream>>>(binsRaw, pairs, t_md, r_d,
      W2_rel + 1 * 2048, W2_root + 0 * 2048, b2 + 0 * 32, y_dm, o_d, N_D, NC_M, BO_MD);
  fused1<8><<<(N_A + 31) / 32, 256, 0, stream>>>(binsRaw, pairs, t_ma, r_a,
      W2_rel + 3 * 2048, W2_root + 2 * 2048, b2 + 2 * 32, y_am, o_a, N_A, NC_M, BO_MA);
  fusedm<<<(N_M + 31) / 32, 256, 0, stream>>>(binsRaw, pairs, t_dm, t_am, r_m,
      W2_rel + 0 * 2048, W2_rel + 2 * 2048, W2_root + 1 * 2048, W2_root + 3 * 2048,
      b2 + 1 * 32, b2 + 3 * 32, y_md, y_ma, o_m, N_M);

  // ---- layer-2 gather, accumulate into d_out ----
  out1<4><<<(N_D + 15) / 16, 256, 0, stream>>>(binsRaw, pairs, y_md, o_d, N_D, NC_M, BO_MD);
  out1<8><<<(N_A + 31) / 32, 256, 0, stream>>>(binsRaw, pairs, y_ma, o_a, N_A, NC_M, BO_MA);
  outm<<<(N_M + 31) / 32, 256, 0, stream>>>(binsRaw, pairs, y_dm, y_am, o_m, N_M);
}

// Round 5
// 1405.807 us; speedup vs baseline: 1.4284x; 1.4284x over previous
//
#include <hip/hip_runtime.h>

#define N_M 100000
#define N_D 30000
#define N_A 80000

// source-chunk binning: 16384 src nodes/chunk (64-wide bf16 rows -> 2.1 MB, fits 4 MB per-XCD L2)
#define CSHIFT 14
#define NC_M 7   // ceil(100000/16384)
#define NC_D 2   // ceil(30000/16384)
#define NC_A 5   // ceil(80000/16384)

// global bin layout: [md: N_D*NC_M | dm: N_M*NC_D | ma: N_A*NC_M | am: N_M*NC_A]
#define BO_MD 0
#define BO_DM (BO_MD + N_D * NC_M)   // 210000
#define BO_MA (BO_DM + N_M * NC_D)   // 410000
#define BO_AM (BO_MA + N_A * NC_M)   // 970000
#define B_TOT (BO_AM + N_M * NC_A)   // 1470000

// 2-level MSD sort: coarse bucket = key>>12 (359 buckets), fine digit = key&4095
#define FBITS 12
#define NFINE 4096
#define NBUCK ((B_TOT + NFINE - 1) / NFINE)   // 359
#define T_A 4096                              // edges per phase-A block

typedef unsigned int u32;
typedef unsigned short u16;
typedef unsigned long long u64;

__device__ __forceinline__ u16 f2bf(float f) {
  u32 u = __float_as_uint(f);
  return (u16)((u + 0x7FFFu + ((u >> 16) & 1u)) >> 16);
}
__device__ __forceinline__ float bf2f(u16 b) {
  return __uint_as_float(((u32)b) << 16);
}
// packed edge: src[31:15] (src<131072), bf16(ew) sans sign in [14:0] (ew>=0)
__device__ __forceinline__ u32 pack_edge(int src, float ew) {
  return ((u32)src << 15) | ((u32)f2bf(ew) & 0x7FFFu);
}
__device__ __forceinline__ float edge_w(u32 p) {
  return __uint_as_float((p & 0x7FFFu) << 16);
}

// ===========================================================================
// Bin build: contiguous-write 2-level counting sort (no scattered 4B stores)
// ===========================================================================
struct Rel { const int* src; const int* dst; const float* ew; int nE; int binBase; int nC; };
struct Rel4 { Rel r[4]; int blkStart[5]; };

// Phase 0: coarse-bucket histogram via LDS staging.
__global__ __launch_bounds__(256) void phase0(Rel4 P, int* __restrict__ bucketHist) {
  __shared__ u32 lh[512];
  int tid = threadIdx.x;
  int b = blockIdx.x, s = 0;
  while (b >= P.blkStart[s + 1]) s++;
  const Rel R = P.r[s];
  int base = (b - P.blkStart[s]) * T_A;
  for (int i = tid; i < 512; i += 256) lh[i] = 0;
  __syncthreads();
#pragma unroll 4
  for (int k = 0; k < 16; k++) {
    int e = base + tid + k * 256;
    if (e < R.nE) {
      int key = R.binBase + R.dst[e] * R.nC + (R.src[e] >> CSHIFT);
      atomicAdd(&lh[key >> FBITS], 1u);
    }
  }
  __syncthreads();
  for (int i = tid; i < 512; i += 256) if (lh[i]) atomicAdd(&bucketHist[i], (int)lh[i]);
}

// 1-block exclusive scan of NBUCK bucket counts -> bucketBase (+sentinel), cursor copy.
__global__ __launch_bounds__(256) void scan_bucket(const int* __restrict__ bucketHist,
                                                   int* __restrict__ bucketBase,
                                                   int* __restrict__ cursor) {
  __shared__ int wsum[4];
  int tid = threadIdx.x;
  int j0 = tid * 2;
  int a0 = (j0 < NBUCK) ? bucketHist[j0] : 0;
  int a1 = (j0 + 1 < NBUCK) ? bucketHist[j0 + 1] : 0;
  int ssum = a0 + a1;
  int lane = tid & 63, wid = tid >> 6;
  int sc = ssum;
#pragma unroll
  for (int off = 1; off < 64; off <<= 1) { int t = __shfl_up(sc, off, 64); if (lane >= off) sc += t; }
  if (lane == 63) wsum[wid] = sc;
  __syncthreads();
  int wex = 0, tot = 0;
  for (int w = 0; w < 4; w++) { int t = wsum[w]; if (w < wid) wex += t; tot += t; }
  int ex = wex + sc - ssum;
  if (j0 < NBUCK) { bucketBase[j0] = ex; cursor[j0] = ex; }
  if (j0 + 1 < NBUCK) { bucketBase[j0 + 1] = ex + a0; cursor[j0 + 1] = ex + a0; }
  if (tid == 0) bucketBase[NBUCK] = tot;
}

// Phase A: partition edges into coarse buckets with contiguous global writes.
__global__ __launch_bounds__(256) void phaseA(Rel4 P, int* __restrict__ cursor,
                                              u64* __restrict__ tmp) {
  __shared__ u32 hist[512], lstart[512], cur[512], gbase[512];
  __shared__ u64 stage[T_A];
  __shared__ u32 wsum[4];
  int tid = threadIdx.x;
  int b = blockIdx.x, s = 0;
  while (b >= P.blkStart[s + 1]) s++;
  const Rel R = P.r[s];
  int base = (b - P.blkStart[s]) * T_A;
  int valid = min(T_A, R.nE - base);
  for (int i = tid; i < 512; i += 256) hist[i] = 0;
  __syncthreads();
#pragma unroll 4
  for (int k = 0; k < 16; k++) {
    int e = base + tid + k * 256;
    if (e < R.nE) {
      int key = R.binBase + R.dst[e] * R.nC + (R.src[e] >> CSHIFT);
      atomicAdd(&hist[key >> FBITS], 1u);
    }
  }
  __syncthreads();
  // scan 512 (2 per thread)
  int c0 = tid * 2;
  u32 h0 = hist[c0], h1 = hist[c0 + 1];
  u32 ssum = h0 + h1;
  int lane = tid & 63, wid = tid >> 6;
  u32 sc = ssum;
#pragma unroll
  for (int off = 1; off < 64; off <<= 1) { int t = __shfl_up((int)sc, off, 64); if (lane >= off) sc += (u32)t; }
  if (lane == 63) wsum[wid] = sc;
  __syncthreads();
  u32 wex = 0;
  for (int w = 0; w < 4; w++) if (w < wid) wex += wsum[w];
  u32 ex = wex + sc - ssum;
  lstart[c0] = ex;       cur[c0] = ex;
  lstart[c0 + 1] = ex + h0; cur[c0 + 1] = ex + h0;
  if (h0) gbase[c0] = (u32)atomicAdd(&cursor[c0], (int)h0);
  if (h1) gbase[c0 + 1] = (u32)atomicAdd(&cursor[c0 + 1], (int)h1);
  __syncthreads();
#pragma unroll 4
  for (int k = 0; k < 16; k++) {
    int e = base + tid + k * 256;
    if (e < R.nE) {
      int srcv = R.src[e];
      int key = R.binBase + R.dst[e] * R.nC + (srcv >> CSHIFT);
      u32 slot = atomicAdd(&cur[key >> FBITS], 1u);
      stage[slot] = ((u64)(u32)key << 32) | pack_edge(srcv, R.ew[e]);
    }
  }
  __syncthreads();
  for (int i = tid; i < valid; i += 256) {
    u64 v = stage[i];
    u32 c = (u32)(v >> (32 + FBITS));
    tmp[gbase[c] + ((u32)i - lstart[c])] = v;
  }
}

// Phase B: per-bucket fine counting sort; writes bins[] rowptr + final pairs.
// Scattered writes confined to ~80 KB per block -> L2-merged full lines.
__global__ __launch_bounds__(256) void phaseB(const u64* __restrict__ tmp,
                                              const int* __restrict__ bucketBase,
                                              u32* __restrict__ pairs,
                                              int* __restrict__ bins) {
  __shared__ u32 h2[NFINE], cur2[NFINE];
  __shared__ u32 wsum[4];
  int c = blockIdx.x, tid = threadIdx.x;
  int s0 = bucketBase[c], s1 = bucketBase[c + 1];
  for (int i = tid; i < NFINE; i += 256) h2[i] = 0;
  __syncthreads();
  for (int e = s0 + tid; e < s1; e += 256) {
    u32 fine = (u32)(tmp[e] >> 32) & (NFINE - 1);
    atomicAdd(&h2[fine], 1u);
  }
  __syncthreads();
  // scan 4096 (16 per thread)
  int f0 = tid * 16;
  u32 v[16], ssum = 0;
#pragma unroll
  for (int i = 0; i < 16; i++) { v[i] = h2[f0 + i]; ssum += v[i]; }
  int lane = tid & 63, wid = tid >> 6;
  u32 sc = ssum;
#pragma unroll
  for (int off = 1; off < 64; off <<= 1) { int t = __shfl_up((int)sc, off, 64); if (lane >= off) sc += (u32)t; }
  if (lane == 63) wsum[wid] = sc;
  __syncthreads();
  u32 wex = 0;
  for (int w = 0; w < 4; w++) if (w < wid) wex += wsum[w];
  u32 ex = wex + sc - ssum;
  int binBase0 = c << FBITS;
#pragma unroll
  for (int i = 0; i < 16; i++) {
    int gb = binBase0 + f0 + i;
    if (gb < B_TOT) bins[gb] = s0 + (int)ex;
    cur2[f0 + i] = ex;
    ex += v[i];
  }
  if (c == NBUCK - 1 && tid == 0) bins[B_TOT] = s1;
  __syncthreads();
  for (int e = s0 + tid; e < s1; e += 256) {
    u64 t = tmp[e];
    u32 fine = (u32)(t >> 32) & (NFINE - 1);
    u32 pos = atomicAdd(&cur2[fine], 1u);
    pairs[s0 + pos] = (u32)t;
  }
}

// ===========================================================================
// Layer-1 dense transforms: t = x @ W1_rel (bf16), r = x @ W1_root + b (bf16)
// ===========================================================================
__global__ __launch_bounds__(256) void l1_tr_m(
    const float* __restrict__ x,
    const float* __restrict__ Wr0, const float* __restrict__ Wr2,
    const float* __restrict__ Wt1, const float* __restrict__ Wt3,
    const float* __restrict__ b1a, const float* __restrict__ b1b,
    u16* __restrict__ t0, u16* __restrict__ t2, u16* __restrict__ r, int n) {
  __shared__ float A[4096], B[4096], C[4096];
  for (int i = threadIdx.x * 4; i < 4096; i += 1024) {
    *(float4*)&A[i] = *(const float4*)&Wr0[i];
    *(float4*)&B[i] = *(const float4*)&Wr2[i];
    float4 p = *(const float4*)&Wt1[i], q = *(const float4*)&Wt3[i];
    *(float4*)&C[i] = make_float4(p.x + q.x, p.y + q.y, p.z + q.z, p.w + q.w);
  }
  __syncthreads();
  int lane = threadIdx.x & 63, wid = threadIdx.x >> 6;
  int wave = blockIdx.x * 4 + wid, nW = gridDim.x * 4;
  float bj = b1a[lane] + b1b[lane];
  for (int base = wave * 4; base < n; base += nW * 4) {
    int n0 = base, n1 = min(base + 1, n - 1), n2 = min(base + 2, n - 1), n3 = min(base + 3, n - 1);
    float o0a = 0, o0b = 0, o0c = bj, o1a = 0, o1b = 0, o1c = bj;
    float o2a = 0, o2b = 0, o2c = bj, o3a = 0, o3b = 0, o3c = bj;
#pragma unroll 4
    for (int k = 0; k < 64; k++) {
      float wa = A[k * 64 + lane], wb = B[k * 64 + lane], wc = C[k * 64 + lane];
      float x0 = x[(size_t)n0 * 64 + k], x1 = x[(size_t)n1 * 64 + k];
      float x2 = x[(size_t)n2 * 64 + k], x3 = x[(size_t)n3 * 64 + k];
      o0a = fmaf(x0, wa, o0a); o0b = fmaf(x0, wb, o0b); o0c = fmaf(x0, wc, o0c);
      o1a = fmaf(x1, wa, o1a); o1b = fmaf(x1, wb, o1b); o1c = fmaf(x1, wc, o1c);
      o2a = fmaf(x2, wa, o2a); o2b = fmaf(x2, wb, o2b); o2c = fmaf(x2, wc, o2c);
      o3a = fmaf(x3, wa, o3a); o3b = fmaf(x3, wb, o3b); o3c = fmaf(x3, wc, o3c);
    }
    t0[(size_t)n0 * 64 + lane] = f2bf(o0a); t2[(size_t)n0 * 64 + lane] = f2bf(o0b); r[(size_t)n0 * 64 + lane] = f2bf(o0c);
    if (base + 1 < n) { t0[(size_t)n1 * 64 + lane] = f2bf(o1a); t2[(size_t)n1 * 64 + lane] = f2bf(o1b); r[(size_t)n1 * 64 + lane] = f2bf(o1c); }
    if (base + 2 < n) { t0[(size_t)n2 * 64 + lane] = f2bf(o2a); t2[(size_t)n2 * 64 + lane] = f2bf(o2b); r[(size_t)n2 * 64 + lane] = f2bf(o2c); }
    if (base + 3 < n) { t0[(size_t)n3 * 64 + lane] = f2bf(o3a); t2[(size_t)n3 * 64 + lane] = f2bf(o3b); r[(size_t)n3 * 64 + lane] = f2bf(o3c); }
  }
}

__global__ __launch_bounds__(256) void l1_tr_s(
    const float* __restrict__ x,
    const float* __restrict__ Wrel, const float* __restrict__ Wroot,
    const float* __restrict__ bias,
    u16* __restrict__ t, u16* __restrict__ r, int n) {
  __shared__ float A[4096], C[4096];
  for (int i = threadIdx.x * 4; i < 4096; i += 1024) {
    *(float4*)&A[i] = *(const float4*)&Wrel[i];
    *(float4*)&C[i] = *(const float4*)&Wroot[i];
  }
  __syncthreads();
  int lane = threadIdx.x & 63, wid = threadIdx.x >> 6;
  int wave = blockIdx.x * 4 + wid, nW = gridDim.x * 4;
  float bj = bias[lane];
  for (int base = wave * 4; base < n; base += nW * 4) {
    int n0 = base, n1 = min(base + 1, n - 1), n2 = min(base + 2, n - 1), n3 = min(base + 3, n - 1);
    float o0a = 0, o0c = bj, o1a = 0, o1c = bj, o2a = 0, o2c = bj, o3a = 0, o3c = bj;
#pragma unroll 4
    for (int k = 0; k < 64; k++) {
      float wa = A[k * 64 + lane], wc = C[k * 64 + lane];
      float x0 = x[(size_t)n0 * 64 + k], x1 = x[(size_t)n1 * 64 + k];
      float x2 = x[(size_t)n2 * 64 + k], x3 = x[(size_t)n3 * 64 + k];
      o0a = fmaf(x0, wa, o0a); o0c = fmaf(x0, wc, o0c);
      o1a = fmaf(x1, wa, o1a); o1c = fmaf(x1, wc, o1c);
      o2a = fmaf(x2, wa, o2a); o2c = fmaf(x2, wc, o2c);
      o3a = fmaf(x3, wa, o3a); o3c = fmaf(x3, wc, o3c);
    }
    t[(size_t)n0 * 64 + lane] = f2bf(o0a); r[(size_t)n0 * 64 + lane] = f2bf(o0c);
    if (base + 1 < n) { t[(size_t)n1 * 64 + lane] = f2bf(o1a); r[(size_t)n1 * 64 + lane] = f2bf(o1c); }
    if (base + 2 < n) { t[(size_t)n2 * 64 + lane] = f2bf(o2a); r[(size_t)n2 * 64 + lane] = f2bf(o2c); }
    if (base + 3 < n) { t[(size_t)n3 * 64 + lane] = f2bf(o3a); r[(size_t)n3 * 64 + lane] = f2bf(o3c); }
  }
}

// ===========================================================================
// Chunk-ordered gather of 64-wide rows into acc[i] (lane = feature).
// ===========================================================================
__device__ __forceinline__ float gatherbin64(
    const int* __restrict__ be, const u32* __restrict__ pairs,
    const u16* __restrict__ tbl, int b, int lane, float a) {
  int e = be[b], s1 = be[b + 1];
  for (; e + 4 <= s1; e += 4) {
    u32 p0 = pairs[e], p1 = pairs[e + 1], p2 = pairs[e + 2], p3 = pairs[e + 3];
    float v0 = bf2f(tbl[(size_t)(p0 >> 15) * 64 + lane]);
    float v1 = bf2f(tbl[(size_t)(p1 >> 15) * 64 + lane]);
    float v2 = bf2f(tbl[(size_t)(p2 >> 15) * 64 + lane]);
    float v3 = bf2f(tbl[(size_t)(p3 >> 15) * 64 + lane]);
    a += edge_w(p0) * v0 + edge_w(p1) * v1 + edge_w(p2) * v2 + edge_w(p3) * v3;
  }
  if (e + 2 <= s1) {
    u32 p0 = pairs[e], p1 = pairs[e + 1];
    a += edge_w(p0) * bf2f(tbl[(size_t)(p0 >> 15) * 64 + lane])
       + edge_w(p1) * bf2f(tbl[(size_t)(p1 >> 15) * 64 + lane]);
    e += 2;
  }
  if (e < s1) { u32 p = pairs[e]; a += edge_w(p) * bf2f(tbl[(size_t)(p >> 15) * 64 + lane]); }
  return a;
}

// Fused: L1 gather (+root, relu) + L2 transform; root/bias part of output
// written directly to d_out (f32); y table (bf16) for the L2 gather.
template<int NPW>
__global__ __launch_bounds__(256) void fused1(
    const int* __restrict__ be, const u32* __restrict__ pairs,
    const u16* __restrict__ tbl, const u16* __restrict__ r1,
    const float* __restrict__ W2r, const float* __restrict__ W2t,
    const float* __restrict__ b2s,
    u16* __restrict__ y, float* __restrict__ oroot,
    int n, int nC, int binBase) {
  __shared__ u16 Wy[2048], Wt[2048];
  __shared__ float bs[32];
  __shared__ float scr[4][64];
  for (int i = threadIdx.x; i < 2048; i += 256) { Wy[i] = f2bf(W2r[i]); Wt[i] = f2bf(W2t[i]); }
  if (threadIdx.x < 32) bs[threadIdx.x] = b2s[threadIdx.x];
  __syncthreads();
  int lane = threadIdx.x & 63, wid = threadIdx.x >> 6;
  int node0 = (blockIdx.x * 4 + wid) * NPW;
  float acc[NPW];
#pragma unroll
  for (int i = 0; i < NPW; i++) acc[i] = 0.f;
  for (int c = 0; c < nC; c++) {
#pragma unroll
    for (int i = 0; i < NPW; i++) {
      int node = node0 + i;
      if (node < n) acc[i] = gatherbin64(be, pairs, tbl, binBase + node * nC + c, lane, acc[i]);
    }
  }
  int j = lane & 31, half = lane >> 5;
#pragma unroll
  for (int i = 0; i < NPW; i++) {
    int node = node0 + i;
    if (node >= n) continue;
    float hv = fmaxf(acc[i] + bf2f(r1[(size_t)node * 64 + lane]), 0.f);
    scr[wid][lane] = hv;
    float oy = 0.f, ot = 0.f;
#pragma unroll
    for (int kk = 0; kk < 32; kk++) {
      int k = (half << 5) + kk;
      float s = scr[wid][k];
      oy = fmaf(s, bf2f(Wy[k * 32 + j]), oy);
      ot = fmaf(s, bf2f(Wt[k * 32 + j]), ot);
    }
    oy += __shfl_xor(oy, 32);
    ot += __shfl_xor(ot, 32);
    if (lane < 32) {
      y[(size_t)node * 32 + lane] = f2bf(oy);
      oroot[(size_t)node * 32 + lane] = ot + bs[lane];
    }
  }
}

// Movie variant: two incoming relations, three L2 matrices.
__global__ __launch_bounds__(256) void fusedm(
    const int* __restrict__ be, const u32* __restrict__ pairs,
    const u16* __restrict__ tbl1,   // t_dm (director rows)
    const u16* __restrict__ tbl2,   // t_am (actor rows)
    const u16* __restrict__ r1,
    const float* __restrict__ W2r0, const float* __restrict__ W2r2,
    const float* __restrict__ W2t1, const float* __restrict__ W2t3,
    const float* __restrict__ b2a, const float* __restrict__ b2b,
    u16* __restrict__ y0, u16* __restrict__ y2, float* __restrict__ oroot, int n) {
  __shared__ u16 Wy0[2048], Wy2[2048], Wt[2048];
  __shared__ float bs[32];
  __shared__ float scr[4][64];
  for (int i = threadIdx.x; i < 2048; i += 256) {
    Wy0[i] = f2bf(W2r0[i]); Wy2[i] = f2bf(W2r2[i]); Wt[i] = f2bf(W2t1[i] + W2t3[i]);
  }
  if (threadIdx.x < 32) bs[threadIdx.x] = b2a[threadIdx.x] + b2b[threadIdx.x];
  __syncthreads();
  int lane = threadIdx.x & 63, wid = threadIdx.x >> 6;
  int node0 = (blockIdx.x * 4 + wid) * 8;
  float acc[8];
#pragma unroll
  for (int i = 0; i < 8; i++) acc[i] = 0.f;
  for (int c = 0; c < NC_D; c++) {
#pragma unroll
    for (int i = 0; i < 8; i++) {
      int node = node0 + i;
      if (node < n) acc[i] = gatherbin64(be, pairs, tbl1, BO_DM + node * NC_D + c, lane, acc[i]);
    }
  }
  for (int c = 0; c < NC_A; c++) {
#pragma unroll
    for (int i = 0; i < 8; i++) {
      int node = node0 + i;
      if (node < n) acc[i] = gatherbin64(be, pairs, tbl2, BO_AM + node * NC_A + c, lane, acc[i]);
    }
  }
  int j = lane & 31, half = lane >> 5;
#pragma unroll
  for (int i = 0; i < 8; i++) {
    int node = node0 + i;
    if (node >= n) continue;
    float hv = fmaxf(acc[i] + bf2f(r1[(size_t)node * 64 + lane]), 0.f);
    scr[wid][lane] = hv;
    float o0 = 0.f, o2 = 0.f, ot = 0.f;
#pragma unroll
    for (int kk = 0; kk < 32; kk++) {
      int k = (half << 5) + kk;
      float s = scr[wid][k];
      o0 = fmaf(s, bf2f(Wy0[k * 32 + j]), o0);
      o2 = fmaf(s, bf2f(Wy2[k * 32 + j]), o2);
      ot = fmaf(s, bf2f(Wt[k * 32 + j]), ot);
    }
    o0 += __shfl_xor(o0, 32);
    o2 += __shfl_xor(o2, 32);
    ot += __shfl_xor(ot, 32);
    if (lane < 32) {
      y0[(size_t)node * 32 + lane] = f2bf(o0);
      y2[(size_t)node * 32 + lane] = f2bf(o2);
      oroot[(size_t)node * 32 + lane] = ot + bs[lane];
    }
  }
}

// ===========================================================================
// Layer-2 gather (32-wide rows, half-wave edge split), accumulating onto the
// root/bias values fused1/fusedm already wrote to d_out.
// ===========================================================================
__device__ __forceinline__ float gatherbin32(
    const int* __restrict__ be, const u32* __restrict__ pairs,
    const u16* __restrict__ ytbl, int b, int j, int half, float a) {
  int e = be[b] + half, s1 = be[b + 1];
  for (; e + 6 < s1; e += 8) {
    u32 p0 = pairs[e], p1 = pairs[e + 2], p2 = pairs[e + 4], p3 = pairs[e + 6];
    a += edge_w(p0) * bf2f(ytbl[(size_t)(p0 >> 15) * 32 + j])
       + edge_w(p1) * bf2f(ytbl[(size_t)(p1 >> 15) * 32 + j])
       + edge_w(p2) * bf2f(ytbl[(size_t)(p2 >> 15) * 32 + j])
       + edge_w(p3) * bf2f(ytbl[(size_t)(p3 >> 15) * 32 + j]);
  }
  for (; e < s1; e += 2) {
    u32 p = pairs[e];
    a += edge_w(p) * bf2f(ytbl[(size_t)(p >> 15) * 32 + j]);
  }
  return a;
}

template<int NPW>
__global__ __launch_bounds__(256) void out1(
    const int* __restrict__ be, const u32* __restrict__ pairs,
    const u16* __restrict__ ytbl, float* __restrict__ out,
    int n, int nC, int binBase) {
  int lane = threadIdx.x & 63, wid = threadIdx.x >> 6;
  int node0 = (blockIdx.x * 4 + wid) * NPW;
  int j = lane & 31, half = lane >> 5;
  float acc[NPW];
#pragma unroll
  for (int i = 0; i < NPW; i++) acc[i] = 0.f;
  for (int c = 0; c < nC; c++) {
#pragma unroll
    for (int i = 0; i < NPW; i++) {
      int node = node0 + i;
      if (node < n) acc[i] = gatherbin32(be, pairs, ytbl, binBase + node * nC + c, j, half, acc[i]);
    }
  }
#pragma unroll
  for (int i = 0; i < NPW; i++) {
    int node = node0 + i;
    if (node >= n) continue;
    float o = acc[i] + __shfl_xor(acc[i], 32);
    if (lane < 32) out[(size_t)node * 32 + lane] += o;
  }
}

__global__ __launch_bounds__(256) void outm(
    const int* __restrict__ be, const u32* __restrict__ pairs,
    const u16* __restrict__ y1,   // y_dm (director rows)
    const u16* __restrict__ y2,   // y_am (actor rows)
    float* __restrict__ out, int n) {
  int lane = threadIdx.x & 63, wid = threadIdx.x >> 6;
  int node0 = (blockIdx.x * 4 + wid) * 8;
  int j = lane & 31, half = lane >> 5;
  float acc[8];
#pragma unroll
  for (int i = 0; i < 8; i++) acc[i] = 0.f;
  for (int c = 0; c < NC_D; c++) {
#pragma unroll
    for (int i = 0; i < 8; i++) {
      int node = node0 + i;
      if (node < n) acc[i] = gatherbin32(be, pairs, y1, BO_DM + node * NC_D + c, j, half, acc[i]);
    }
  }
  for (int c = 0; c < NC_A; c++) {
#pragma unroll
    for (int i = 0; i < 8; i++) {
      int node = node0 + i;
      if (node < n) acc[i] = gatherbin32(be, pairs, y2, BO_AM + node * NC_A + c, j, half, acc[i]);
    }
  }
#pragma unroll
  for (int i = 0; i < 8; i++) {
    int node = node0 + i;
    if (node >= n) continue;
    float o = acc[i] + __shfl_xor(acc[i], 32);
    if (lane < 32) out[(size_t)node * 32 + lane] += o;
  }
}

static inline int nblkA(long long e) { return (int)((e + T_A - 1) / T_A); }

extern "C" void kernel_launch(void* const* d_in, const int* in_sizes, int n_in,
                              void* d_out, int out_size, void* d_ws, size_t ws_size,
                              hipStream_t stream) {
  const float* x_m = (const float*)d_in[0];
  const float* x_d = (const float*)d_in[1];
  const float* x_a = (const float*)d_in[2];
  const int* src_md = (const int*)d_in[3];
  const int* dst_md = (const int*)d_in[4];
  const float* ew_md = (const float*)d_in[5];
  const int* src_dm = (const int*)d_in[6];
  const int* dst_dm = (const int*)d_in[7];
  const float* ew_dm = (const float*)d_in[8];
  const int* src_ma = (const int*)d_in[9];
  const int* dst_ma = (const int*)d_in[10];
  const float* ew_ma = (const float*)d_in[11];
  const int* src_am = (const int*)d_in[12];
  const int* dst_am = (const int*)d_in[13];
  const float* ew_am = (const float*)d_in[14];
  const float* W1_rel = (const float*)d_in[15];
  const float* b1 = (const float*)d_in[16];
  const float* W1_root = (const float*)d_in[17];
  const float* W2_rel = (const float*)d_in[18];
  const float* b2 = (const float*)d_in[19];
  const float* W2_root = (const float*)d_in[20];

  const int E_md = in_sizes[3];
  const int E_dm = in_sizes[6];
  const int E_ma = in_sizes[9];
  const int E_am = in_sizes[12];
  const long long E_tot = (long long)E_md + E_dm + E_ma + E_am;

  // ---- workspace ----
  // tmp (u64, 8B-aligned, first) is dead after phaseB; bf16 tables alias it.
  char* w = (char*)d_ws;
  u64* tmp = (u64*)w;       w += (size_t)E_tot * 8;
  u32* pairs = (u32*)w;     w += (size_t)E_tot * 4;
  int* bins = (int*)w;      w += (size_t)(B_TOT + 1) * 4;
  int* bucketHist = (int*)w; w += 512 * 4;
  int* bucketBase = (int*)w; w += (NBUCK + 1) * 4;
  int* cursor = (int*)w;     w += 512 * 4;
  u16* r_d  = (u16*)w;      w += (size_t)N_D * 64 * 2;
  u16* r_a  = (u16*)w;      w += (size_t)N_A * 64 * 2;
  u16* y_md = (u16*)w;      w += (size_t)N_M * 32 * 2;
  u16* y_dm = (u16*)w;      w += (size_t)N_D * 32 * 2;
  u16* y_ma = (u16*)w;      w += (size_t)N_M * 32 * 2;
  u16* y_am = (u16*)w;      w += (size_t)N_A * 32 * 2;
  if ((size_t)(w - (char*)d_ws) > ws_size) return;
  // tables aliasing tmp (written only after phaseB has consumed tmp)
  char* ta = (char*)tmp;
  u16* t_md = (u16*)ta;     ta += (size_t)N_M * 64 * 2;
  u16* t_dm = (u16*)ta;     ta += (size_t)N_D * 64 * 2;
  u16* t_ma = (u16*)ta;     ta += (size_t)N_M * 64 * 2;
  u16* t_am = (u16*)ta;     ta += (size_t)N_A * 64 * 2;
  u16* r_m  = (u16*)ta;     ta += (size_t)N_M * 64 * 2;

  float* o_m = (float*)d_out;
  float* o_d = o_m + (size_t)N_M * 32;
  float* o_a = o_d + (size_t)N_D * 32;

  // ---- bin build: 2-level counting sort ----
  hipMemsetAsync(bucketHist, 0, 512 * 4, stream);

  Rel4 P;
  P.r[0] = { src_md, dst_md, ew_md, E_md, BO_MD, NC_M };
  P.r[1] = { src_dm, dst_dm, ew_dm, E_dm, BO_DM, NC_D };
  P.r[2] = { src_ma, dst_ma, ew_ma, E_ma, BO_MA, NC_M };
  P.r[3] = { src_am, dst_am, ew_am, E_am, BO_AM, NC_A };
  P.blkStart[0] = 0;
  P.blkStart[1] = P.blkStart[0] + nblkA(E_md);
  P.blkStart[2] = P.blkStart[1] + nblkA(E_dm);
  P.blkStart[3] = P.blkStart[2] + nblkA(E_ma);
  P.blkStart[4] = P.blkStart[3] + nblkA(E_am);

  phase0<<<P.blkStart[4], 256, 0, stream>>>(P, bucketHist);
  scan_bucket<<<1, 256, 0, stream>>>(bucketHist, bucketBase, cursor);
  phaseA<<<P.blkStart[4], 256, 0, stream>>>(P, cursor, tmp);
  phaseB<<<NBUCK, 256, 0, stream>>>(tmp, bucketBase, pairs, bins);

  // ---- layer-1 dense transforms (write into tmp-aliased tables) ----
  l1_tr_m<<<768, 256, 0, stream>>>(x_m, W1_rel + 0 * 4096, W1_rel + 2 * 4096,
                                   W1_root + 1 * 4096, W1_root + 3 * 4096,
                                   b1 + 1 * 64, b1 + 3 * 64, t_md, t_ma, r_m, N_M);
  l1_tr_s<<<512, 256, 0, stream>>>(x_d, W1_rel + 1 * 4096, W1_root + 0 * 4096,
                                   b1 + 0 * 64, t_dm, r_d, N_D);
  l1_tr_s<<<512, 256, 0, stream>>>(x_a, W1_rel + 3 * 4096, W1_root + 2 * 4096,
                                   b1 + 2 * 64, t_am, r_a, N_A);

  // ---- fused L1-gather + L2-transform (writes root part to d_out) ----
  fused1<4><<<(N_D + 15) / 16, 256, 0, stream>>>(bins, pairs, t_md, r_d,
      W2_rel + 1 * 2048, W2_root + 0 * 2048, b2 + 0 * 32, y_dm, o_d, N_D, NC_M, BO_MD);
  fused1<8><<<(N_A + 31) / 32, 256, 0, stream>>>(bins, pairs, t_ma, r_a,
      W2_rel + 3 * 2048, W2_root + 2 * 2048, b2 + 2 * 32, y_am, o_a, N_A, NC_M, BO_MA);
  fusedm<<<(N_M + 31) / 32, 256, 0, stream>>>(bins, pairs, t_dm, t_am, r_m,
      W2_rel + 0 * 2048, W2_rel + 2 * 2048, W2_root + 1 * 2048, W2_root + 3 * 2048,
      b2 + 1 * 32, b2 + 3 * 32, y_md, y_ma, o_m, N_M);

  // ---- layer-2 gather, accumulate into d_out ----
  out1<4><<<(N_D + 15) / 16, 256, 0, stream>>>(bins, pairs, y_md, o_d, N_D, NC_M, BO_MD);
  out1<8><<<(N_A + 31) / 32, 256, 0, stream>>>(bins, pairs, y_ma, o_a, N_A, NC_M, BO_MA);
  outm<<<(N_M + 31) / 32, 256, 0, stream>>>(bins, pairs, y_dm, y_am, o_m, N_M);
}

// Round 6
// 1184.739 us; speedup vs baseline: 1.6949x; 1.1866x over previous
//
#include <hip/hip_runtime.h>

#define N_M 100000
#define N_D 30000
#define N_A 80000

// source-chunk binning: 16384 src nodes/chunk (64-wide bf16 rows -> 2.1 MB, fits 4 MB per-XCD L2)
#define CSHIFT 14
#define NC_M 7   // ceil(100000/16384)
#define NC_D 2   // ceil(30000/16384)
#define NC_A 5   // ceil(80000/16384)

// global bin layout: [md: N_D*NC_M | dm: N_M*NC_D | ma: N_A*NC_M | am: N_M*NC_A]
#define BO_MD 0
#define BO_DM (BO_MD + N_D * NC_M)   // 210000
#define BO_MA (BO_DM + N_M * NC_D)   // 410000
#define BO_AM (BO_MA + N_A * NC_M)   // 970000
#define B_TOT (BO_AM + N_M * NC_A)   // 1470000

// 2-level MSD sort: coarse bucket = key>>12 (359 buckets), fine digit = key&4095
#define FBITS 12
#define NFINE 4096
#define NBUCK ((B_TOT + NFINE - 1) / NFINE)   // 359
#define T_A 4096                              // edges per phase-A block

typedef unsigned int u32;
typedef unsigned short u16;
typedef unsigned long long u64;

__device__ __forceinline__ u16 f2bf(float f) {
  u32 u = __float_as_uint(f);
  return (u16)((u + 0x7FFFu + ((u >> 16) & 1u)) >> 16);
}
__device__ __forceinline__ float bf2f(u16 b) {
  return __uint_as_float(((u32)b) << 16);
}
// packed edge: src[31:15] (src<131072), bf16(ew) sans sign in [14:0] (ew>=0)
__device__ __forceinline__ u32 pack_edge(int src, float ew) {
  return ((u32)src << 15) | ((u32)f2bf(ew) & 0x7FFFu);
}
__device__ __forceinline__ float edge_w(u32 p) {
  return __uint_as_float((p & 0x7FFFu) << 16);
}

// ===========================================================================
// Bin build: contiguous-write 2-level counting sort (unchanged from R5)
// ===========================================================================
struct Rel { const int* src; const int* dst; const float* ew; int nE; int binBase; int nC; };
struct Rel4 { Rel r[4]; int blkStart[5]; };

__global__ __launch_bounds__(256) void phase0(Rel4 P, int* __restrict__ bucketHist) {
  __shared__ u32 lh[512];
  int tid = threadIdx.x;
  int b = blockIdx.x, s = 0;
  while (b >= P.blkStart[s + 1]) s++;
  const Rel R = P.r[s];
  int base = (b - P.blkStart[s]) * T_A;
  for (int i = tid; i < 512; i += 256) lh[i] = 0;
  __syncthreads();
#pragma unroll 4
  for (int k = 0; k < 16; k++) {
    int e = base + tid + k * 256;
    if (e < R.nE) {
      int key = R.binBase + R.dst[e] * R.nC + (R.src[e] >> CSHIFT);
      atomicAdd(&lh[key >> FBITS], 1u);
    }
  }
  __syncthreads();
  for (int i = tid; i < 512; i += 256) if (lh[i]) atomicAdd(&bucketHist[i], (int)lh[i]);
}

__global__ __launch_bounds__(256) void scan_bucket(const int* __restrict__ bucketHist,
                                                   int* __restrict__ bucketBase,
                                                   int* __restrict__ cursor) {
  __shared__ int wsum[4];
  int tid = threadIdx.x;
  int j0 = tid * 2;
  int a0 = (j0 < NBUCK) ? bucketHist[j0] : 0;
  int a1 = (j0 + 1 < NBUCK) ? bucketHist[j0 + 1] : 0;
  int ssum = a0 + a1;
  int lane = tid & 63, wid = tid >> 6;
  int sc = ssum;
#pragma unroll
  for (int off = 1; off < 64; off <<= 1) { int t = __shfl_up(sc, off, 64); if (lane >= off) sc += t; }
  if (lane == 63) wsum[wid] = sc;
  __syncthreads();
  int wex = 0, tot = 0;
  for (int w = 0; w < 4; w++) { int t = wsum[w]; if (w < wid) wex += t; tot += t; }
  int ex = wex + sc - ssum;
  if (j0 < NBUCK) { bucketBase[j0] = ex; cursor[j0] = ex; }
  if (j0 + 1 < NBUCK) { bucketBase[j0 + 1] = ex + a0; cursor[j0 + 1] = ex + a0; }
  if (tid == 0) bucketBase[NBUCK] = tot;
}

__global__ __launch_bounds__(256) void phaseA(Rel4 P, int* __restrict__ cursor,
                                              u64* __restrict__ tmp) {
  __shared__ u32 hist[512], lstart[512], cur[512], gbase[512];
  __shared__ u64 stage[T_A];
  __shared__ u32 wsum[4];
  int tid = threadIdx.x;
  int b = blockIdx.x, s = 0;
  while (b >= P.blkStart[s + 1]) s++;
  const Rel R = P.r[s];
  int base = (b - P.blkStart[s]) * T_A;
  int valid = min(T_A, R.nE - base);
  for (int i = tid; i < 512; i += 256) hist[i] = 0;
  __syncthreads();
#pragma unroll 4
  for (int k = 0; k < 16; k++) {
    int e = base + tid + k * 256;
    if (e < R.nE) {
      int key = R.binBase + R.dst[e] * R.nC + (R.src[e] >> CSHIFT);
      atomicAdd(&hist[key >> FBITS], 1u);
    }
  }
  __syncthreads();
  int c0 = tid * 2;
  u32 h0 = hist[c0], h1 = hist[c0 + 1];
  u32 ssum = h0 + h1;
  int lane = tid & 63, wid = tid >> 6;
  u32 sc = ssum;
#pragma unroll
  for (int off = 1; off < 64; off <<= 1) { int t = __shfl_up((int)sc, off, 64); if (lane >= off) sc += (u32)t; }
  if (lane == 63) wsum[wid] = sc;
  __syncthreads();
  u32 wex = 0;
  for (int w = 0; w < 4; w++) if (w < wid) wex += wsum[w];
  u32 ex = wex + sc - ssum;
  lstart[c0] = ex;       cur[c0] = ex;
  lstart[c0 + 1] = ex + h0; cur[c0 + 1] = ex + h0;
  if (h0) gbase[c0] = (u32)atomicAdd(&cursor[c0], (int)h0);
  if (h1) gbase[c0 + 1] = (u32)atomicAdd(&cursor[c0 + 1], (int)h1);
  __syncthreads();
#pragma unroll 4
  for (int k = 0; k < 16; k++) {
    int e = base + tid + k * 256;
    if (e < R.nE) {
      int srcv = R.src[e];
      int key = R.binBase + R.dst[e] * R.nC + (srcv >> CSHIFT);
      u32 slot = atomicAdd(&cur[key >> FBITS], 1u);
      stage[slot] = ((u64)(u32)key << 32) | pack_edge(srcv, R.ew[e]);
    }
  }
  __syncthreads();
  for (int i = tid; i < valid; i += 256) {
    u64 v = stage[i];
    u32 c = (u32)(v >> (32 + FBITS));
    tmp[gbase[c] + ((u32)i - lstart[c])] = v;
  }
}

__global__ __launch_bounds__(256) void phaseB(const u64* __restrict__ tmp,
                                              const int* __restrict__ bucketBase,
                                              u32* __restrict__ pairs,
                                              int* __restrict__ bins) {
  __shared__ u32 h2[NFINE], cur2[NFINE];
  __shared__ u32 wsum[4];
  int c = blockIdx.x, tid = threadIdx.x;
  int s0 = bucketBase[c], s1 = bucketBase[c + 1];
  for (int i = tid; i < NFINE; i += 256) h2[i] = 0;
  __syncthreads();
  for (int e = s0 + tid; e < s1; e += 256) {
    u32 fine = (u32)(tmp[e] >> 32) & (NFINE - 1);
    atomicAdd(&h2[fine], 1u);
  }
  __syncthreads();
  int f0 = tid * 16;
  u32 v[16], ssum = 0;
#pragma unroll
  for (int i = 0; i < 16; i++) { v[i] = h2[f0 + i]; ssum += v[i]; }
  int lane = tid & 63, wid = tid >> 6;
  u32 sc = ssum;
#pragma unroll
  for (int off = 1; off < 64; off <<= 1) { int t = __shfl_up((int)sc, off, 64); if (lane >= off) sc += (u32)t; }
  if (lane == 63) wsum[wid] = sc;
  __syncthreads();
  u32 wex = 0;
  for (int w = 0; w < 4; w++) if (w < wid) wex += wsum[w];
  u32 ex = wex + sc - ssum;
  int binBase0 = c << FBITS;
#pragma unroll
  for (int i = 0; i < 16; i++) {
    int gb = binBase0 + f0 + i;
    if (gb < B_TOT) bins[gb] = s0 + (int)ex;
    cur2[f0 + i] = ex;
    ex += v[i];
  }
  if (c == NBUCK - 1 && tid == 0) bins[B_TOT] = s1;
  __syncthreads();
  for (int e = s0 + tid; e < s1; e += 256) {
    u64 t = tmp[e];
    u32 fine = (u32)(t >> 32) & (NFINE - 1);
    u32 pos = atomicAdd(&cur2[fine], 1u);
    pairs[s0 + pos] = (u32)t;
  }
}

// ===========================================================================
// Layer-1 dense transforms (unchanged from R5)
// ===========================================================================
__global__ __launch_bounds__(256) void l1_tr_m(
    const float* __restrict__ x,
    const float* __restrict__ Wr0, const float* __restrict__ Wr2,
    const float* __restrict__ Wt1, const float* __restrict__ Wt3,
    const float* __restrict__ b1a, const float* __restrict__ b1b,
    u16* __restrict__ t0, u16* __restrict__ t2, u16* __restrict__ r, int n) {
  __shared__ float A[4096], B[4096], C[4096];
  for (int i = threadIdx.x * 4; i < 4096; i += 1024) {
    *(float4*)&A[i] = *(const float4*)&Wr0[i];
    *(float4*)&B[i] = *(const float4*)&Wr2[i];
    float4 p = *(const float4*)&Wt1[i], q = *(const float4*)&Wt3[i];
    *(float4*)&C[i] = make_float4(p.x + q.x, p.y + q.y, p.z + q.z, p.w + q.w);
  }
  __syncthreads();
  int lane = threadIdx.x & 63, wid = threadIdx.x >> 6;
  int wave = blockIdx.x * 4 + wid, nW = gridDim.x * 4;
  float bj = b1a[lane] + b1b[lane];
  for (int base = wave * 4; base < n; base += nW * 4) {
    int n0 = base, n1 = min(base + 1, n - 1), n2 = min(base + 2, n - 1), n3 = min(base + 3, n - 1);
    float o0a = 0, o0b = 0, o0c = bj, o1a = 0, o1b = 0, o1c = bj;
    float o2a = 0, o2b = 0, o2c = bj, o3a = 0, o3b = 0, o3c = bj;
#pragma unroll 4
    for (int k = 0; k < 64; k++) {
      float wa = A[k * 64 + lane], wb = B[k * 64 + lane], wc = C[k * 64 + lane];
      float x0 = x[(size_t)n0 * 64 + k], x1 = x[(size_t)n1 * 64 + k];
      float x2 = x[(size_t)n2 * 64 + k], x3 = x[(size_t)n3 * 64 + k];
      o0a = fmaf(x0, wa, o0a); o0b = fmaf(x0, wb, o0b); o0c = fmaf(x0, wc, o0c);
      o1a = fmaf(x1, wa, o1a); o1b = fmaf(x1, wb, o1b); o1c = fmaf(x1, wc, o1c);
      o2a = fmaf(x2, wa, o2a); o2b = fmaf(x2, wb, o2b); o2c = fmaf(x2, wc, o2c);
      o3a = fmaf(x3, wa, o3a); o3b = fmaf(x3, wb, o3b); o3c = fmaf(x3, wc, o3c);
    }
    t0[(size_t)n0 * 64 + lane] = f2bf(o0a); t2[(size_t)n0 * 64 + lane] = f2bf(o0b); r[(size_t)n0 * 64 + lane] = f2bf(o0c);
    if (base + 1 < n) { t0[(size_t)n1 * 64 + lane] = f2bf(o1a); t2[(size_t)n1 * 64 + lane] = f2bf(o1b); r[(size_t)n1 * 64 + lane] = f2bf(o1c); }
    if (base + 2 < n) { t0[(size_t)n2 * 64 + lane] = f2bf(o2a); t2[(size_t)n2 * 64 + lane] = f2bf(o2b); r[(size_t)n2 * 64 + lane] = f2bf(o2c); }
    if (base + 3 < n) { t0[(size_t)n3 * 64 + lane] = f2bf(o3a); t2[(size_t)n3 * 64 + lane] = f2bf(o3b); r[(size_t)n3 * 64 + lane] = f2bf(o3c); }
  }
}

__global__ __launch_bounds__(256) void l1_tr_s(
    const float* __restrict__ x,
    const float* __restrict__ Wrel, const float* __restrict__ Wroot,
    const float* __restrict__ bias,
    u16* __restrict__ t, u16* __restrict__ r, int n) {
  __shared__ float A[4096], C[4096];
  for (int i = threadIdx.x * 4; i < 4096; i += 1024) {
    *(float4*)&A[i] = *(const float4*)&Wrel[i];
    *(float4*)&C[i] = *(const float4*)&Wroot[i];
  }
  __syncthreads();
  int lane = threadIdx.x & 63, wid = threadIdx.x >> 6;
  int wave = blockIdx.x * 4 + wid, nW = gridDim.x * 4;
  float bj = bias[lane];
  for (int base = wave * 4; base < n; base += nW * 4) {
    int n0 = base, n1 = min(base + 1, n - 1), n2 = min(base + 2, n - 1), n3 = min(base + 3, n - 1);
    float o0a = 0, o0c = bj, o1a = 0, o1c = bj, o2a = 0, o2c = bj, o3a = 0, o3c = bj;
#pragma unroll 4
    for (int k = 0; k < 64; k++) {
      float wa = A[k * 64 + lane], wc = C[k * 64 + lane];
      float x0 = x[(size_t)n0 * 64 + k], x1 = x[(size_t)n1 * 64 + k];
      float x2 = x[(size_t)n2 * 64 + k], x3 = x[(size_t)n3 * 64 + k];
      o0a = fmaf(x0, wa, o0a); o0c = fmaf(x0, wc, o0c);
      o1a = fmaf(x1, wa, o1a); o1c = fmaf(x1, wc, o1c);
      o2a = fmaf(x2, wa, o2a); o2c = fmaf(x2, wc, o2c);
      o3a = fmaf(x3, wa, o3a); o3c = fmaf(x3, wc, o3c);
    }
    t[(size_t)n0 * 64 + lane] = f2bf(o0a); r[(size_t)n0 * 64 + lane] = f2bf(o0c);
    if (base + 1 < n) { t[(size_t)n1 * 64 + lane] = f2bf(o1a); r[(size_t)n1 * 64 + lane] = f2bf(o1c); }
    if (base + 2 < n) { t[(size_t)n2 * 64 + lane] = f2bf(o2a); r[(size_t)n2 * 64 + lane] = f2bf(o2c); }
    if (base + 3 < n) { t[(size_t)n3 * 64 + lane] = f2bf(o3a); r[(size_t)n3 * 64 + lane] = f2bf(o3c); }
  }
}

// ===========================================================================
// Scalarized gathers. Bounds come in as wave-uniform (readfirstlane'd) sgprs;
// pair loads are wave-uniform -> scalar cache; per-edge vector work = 1 VMEM
// load + cvt + fma.
// ===========================================================================
__device__ __forceinline__ float gather_run64(
    int s0, int s1, const u32* __restrict__ pairs,
    const u16* __restrict__ tbl, int lane, float a) {
  int e = s0;
  for (; e + 4 <= s1; e += 4) {
    u32 p0 = __builtin_amdgcn_readfirstlane(pairs[e]);
    u32 p1 = __builtin_amdgcn_readfirstlane(pairs[e + 1]);
    u32 p2 = __builtin_amdgcn_readfirstlane(pairs[e + 2]);
    u32 p3 = __builtin_amdgcn_readfirstlane(pairs[e + 3]);
    float v0 = bf2f(tbl[(size_t)(p0 >> 15) * 64 + lane]);
    float v1 = bf2f(tbl[(size_t)(p1 >> 15) * 64 + lane]);
    float v2 = bf2f(tbl[(size_t)(p2 >> 15) * 64 + lane]);
    float v3 = bf2f(tbl[(size_t)(p3 >> 15) * 64 + lane]);
    a = fmaf(edge_w(p0), v0, a);
    a = fmaf(edge_w(p1), v1, a);
    a = fmaf(edge_w(p2), v2, a);
    a = fmaf(edge_w(p3), v3, a);
  }
  for (; e < s1; e++) {
    u32 p = __builtin_amdgcn_readfirstlane(pairs[e]);
    a = fmaf(edge_w(p), bf2f(tbl[(size_t)(p >> 15) * 64 + lane]), a);
  }
  return a;
}

__device__ __forceinline__ float gather_run32(
    int s0, int s1, const u32* __restrict__ pairs,
    const u16* __restrict__ ytbl, int j, int half, float a) {
  int e = s0;
  for (; e + 4 <= s1; e += 4) {
    u32 pa0 = __builtin_amdgcn_readfirstlane(pairs[e]);
    u32 pb0 = __builtin_amdgcn_readfirstlane(pairs[e + 1]);
    u32 pa1 = __builtin_amdgcn_readfirstlane(pairs[e + 2]);
    u32 pb1 = __builtin_amdgcn_readfirstlane(pairs[e + 3]);
    u32 p0 = half ? pb0 : pa0;
    u32 p1 = half ? pb1 : pa1;
    float v0 = bf2f(ytbl[(size_t)(p0 >> 15) * 32 + j]);
    float v1 = bf2f(ytbl[(size_t)(p1 >> 15) * 32 + j]);
    a = fmaf(edge_w(p0), v0, a);
    a = fmaf(edge_w(p1), v1, a);
  }
  if (e + 2 <= s1) {
    u32 pa = __builtin_amdgcn_readfirstlane(pairs[e]);
    u32 pb = __builtin_amdgcn_readfirstlane(pairs[e + 1]);
    u32 p = half ? pb : pa;
    a = fmaf(edge_w(p), bf2f(ytbl[(size_t)(p >> 15) * 32 + j]), a);
    e += 2;
  }
  if (e < s1) {
    u32 p = __builtin_amdgcn_readfirstlane(pairs[e]);
    if (half == 0) a = fmaf(edge_w(p), bf2f(ytbl[(size_t)(p >> 15) * 32 + j]), a);
  }
  return a;
}

// Fused: L1 gather (+root, relu) + L2 transform. NPW=8 nodes/wave; all bin
// boundaries for the wave preloaded into one VGPR, extracted via readlane.
__global__ __launch_bounds__(256) void fused1(
    const int* __restrict__ bins, const u32* __restrict__ pairs,
    const u16* __restrict__ tbl, const u16* __restrict__ r1,
    const float* __restrict__ W2r, const float* __restrict__ W2t,
    const float* __restrict__ b2s,
    u16* __restrict__ y, float* __restrict__ oroot,
    int n, int nC, int binBase) {
  __shared__ u16 Wy[2048], Wt[2048];
  __shared__ float bs[32];
  __shared__ float scr[4][64];
  for (int i = threadIdx.x; i < 2048; i += 256) { Wy[i] = f2bf(W2r[i]); Wt[i] = f2bf(W2t[i]); }
  if (threadIdx.x < 32) bs[threadIdx.x] = b2s[threadIdx.x];
  __syncthreads();
  int lane = threadIdx.x & 63, wid = threadIdx.x >> 6;
  int node0 = (blockIdx.x * 4 + wid) * 8;
  int bnd = bins[binBase + node0 * nC + min(lane, 8 * nC)];
  float acc[8];
#pragma unroll
  for (int i = 0; i < 8; i++) acc[i] = 0.f;
  for (int c = 0; c < nC; c++) {
#pragma unroll
    for (int i = 0; i < 8; i++) {
      int s0 = __builtin_amdgcn_readlane(bnd, i * nC + c);
      int s1 = __builtin_amdgcn_readlane(bnd, i * nC + c + 1);
      if (node0 + i < n) acc[i] = gather_run64(s0, s1, pairs, tbl, lane, acc[i]);
    }
  }
  int j = lane & 31, half = lane >> 5;
#pragma unroll
  for (int i = 0; i < 8; i++) {
    int node = node0 + i;
    if (node >= n) continue;
    float hv = fmaxf(acc[i] + bf2f(r1[(size_t)node * 64 + lane]), 0.f);
    scr[wid][lane] = hv;
    float oy = 0.f, ot = 0.f;
#pragma unroll
    for (int kk = 0; kk < 32; kk++) {
      int k = (half << 5) + kk;
      float s = scr[wid][k];
      oy = fmaf(s, bf2f(Wy[k * 32 + j]), oy);
      ot = fmaf(s, bf2f(Wt[k * 32 + j]), ot);
    }
    oy += __shfl_xor(oy, 32);
    ot += __shfl_xor(ot, 32);
    if (lane < 32) {
      y[(size_t)node * 32 + lane] = f2bf(oy);
      oroot[(size_t)node * 32 + lane] = ot + bs[lane];
    }
  }
}

// Movie variant: two incoming relations (dm, am), three L2 matrices.
__global__ __launch_bounds__(256) void fusedm(
    const int* __restrict__ bins, const u32* __restrict__ pairs,
    const u16* __restrict__ tbl1,   // t_dm (director rows)
    const u16* __restrict__ tbl2,   // t_am (actor rows)
    const u16* __restrict__ r1,
    const float* __restrict__ W2r0, const float* __restrict__ W2r2,
    const float* __restrict__ W2t1, const float* __restrict__ W2t3,
    const float* __restrict__ b2a, const float* __restrict__ b2b,
    u16* __restrict__ y0, u16* __restrict__ y2, float* __restrict__ oroot, int n) {
  __shared__ u16 Wy0[2048], Wy2[2048], Wt[2048];
  __shared__ float bs[32];
  __shared__ float scr[4][64];
  for (int i = threadIdx.x; i < 2048; i += 256) {
    Wy0[i] = f2bf(W2r0[i]); Wy2[i] = f2bf(W2r2[i]); Wt[i] = f2bf(W2t1[i] + W2t3[i]);
  }
  if (threadIdx.x < 32) bs[threadIdx.x] = b2a[threadIdx.x] + b2b[threadIdx.x];
  __syncthreads();
  int lane = threadIdx.x & 63, wid = threadIdx.x >> 6;
  int node0 = (blockIdx.x * 4 + wid) * 8;
  int bdm = bins[BO_DM + node0 * NC_D + min(lane, 8 * NC_D)];
  int bam = bins[BO_AM + node0 * NC_A + min(lane, 8 * NC_A)];
  float acc[8];
#pragma unroll
  for (int i = 0; i < 8; i++) acc[i] = 0.f;
#pragma unroll
  for (int c = 0; c < NC_D; c++) {
#pragma unroll
    for (int i = 0; i < 8; i++) {
      int s0 = __builtin_amdgcn_readlane(bdm, i * NC_D + c);
      int s1 = __builtin_amdgcn_readlane(bdm, i * NC_D + c + 1);
      if (node0 + i < n) acc[i] = gather_run64(s0, s1, pairs, tbl1, lane, acc[i]);
    }
  }
#pragma unroll
  for (int c = 0; c < NC_A; c++) {
#pragma unroll
    for (int i = 0; i < 8; i++) {
      int s0 = __builtin_amdgcn_readlane(bam, i * NC_A + c);
      int s1 = __builtin_amdgcn_readlane(bam, i * NC_A + c + 1);
      if (node0 + i < n) acc[i] = gather_run64(s0, s1, pairs, tbl2, lane, acc[i]);
    }
  }
  int j = lane & 31, half = lane >> 5;
#pragma unroll
  for (int i = 0; i < 8; i++) {
    int node = node0 + i;
    if (node >= n) continue;
    float hv = fmaxf(acc[i] + bf2f(r1[(size_t)node * 64 + lane]), 0.f);
    scr[wid][lane] = hv;
    float o0 = 0.f, o2 = 0.f, ot = 0.f;
#pragma unroll
    for (int kk = 0; kk < 32; kk++) {
      int k = (half << 5) + kk;
      float s = scr[wid][k];
      o0 = fmaf(s, bf2f(Wy0[k * 32 + j]), o0);
      o2 = fmaf(s, bf2f(Wy2[k * 32 + j]), o2);
      ot = fmaf(s, bf2f(Wt[k * 32 + j]), ot);
    }
    o0 += __shfl_xor(o0, 32);
    o2 += __shfl_xor(o2, 32);
    ot += __shfl_xor(ot, 32);
    if (lane < 32) {
      y0[(size_t)node * 32 + lane] = f2bf(o0);
      y2[(size_t)node * 32 + lane] = f2bf(o2);
      oroot[(size_t)node * 32 + lane] = ot + bs[lane];
    }
  }
}

// Layer-2 gather (32-wide rows), accumulating onto root/bias already in d_out.
__global__ __launch_bounds__(256) void out1(
    const int* __restrict__ bins, const u32* __restrict__ pairs,
    const u16* __restrict__ ytbl, float* __restrict__ out,
    int n, int nC, int binBase) {
  int lane = threadIdx.x & 63, wid = threadIdx.x >> 6;
  int node0 = (blockIdx.x * 4 + wid) * 8;
  int j = lane & 31, half = lane >> 5;
  int bnd = bins[binBase + node0 * nC + min(lane, 8 * nC)];
  float acc[8];
#pragma unroll
  for (int i = 0; i < 8; i++) acc[i] = 0.f;
  for (int c = 0; c < nC; c++) {
#pragma unroll
    for (int i = 0; i < 8; i++) {
      int s0 = __builtin_amdgcn_readlane(bnd, i * nC + c);
      int s1 = __builtin_amdgcn_readlane(bnd, i * nC + c + 1);
      if (node0 + i < n) acc[i] = gather_run32(s0, s1, pairs, ytbl, j, half, acc[i]);
    }
  }
#pragma unroll
  for (int i = 0; i < 8; i++) {
    int node = node0 + i;
    if (node >= n) continue;
    float o = acc[i] + __shfl_xor(acc[i], 32);
    if (lane < 32) out[(size_t)node * 32 + lane] += o;
  }
}

__global__ __launch_bounds__(256) void outm(
    const int* __restrict__ bins, const u32* __restrict__ pairs,
    const u16* __restrict__ y1,   // y_dm (director rows)
    const u16* __restrict__ y2,   // y_am (actor rows)
    float* __restrict__ out, int n) {
  int lane = threadIdx.x & 63, wid = threadIdx.x >> 6;
  int node0 = (blockIdx.x * 4 + wid) * 8;
  int j = lane & 31, half = lane >> 5;
  int bdm = bins[BO_DM + node0 * NC_D + min(lane, 8 * NC_D)];
  int bam = bins[BO_AM + node0 * NC_A + min(lane, 8 * NC_A)];
  float acc[8];
#pragma unroll
  for (int i = 0; i < 8; i++) acc[i] = 0.f;
#pragma unroll
  for (int c = 0; c < NC_D; c++) {
#pragma unroll
    for (int i = 0; i < 8; i++) {
      int s0 = __builtin_amdgcn_readlane(bdm, i * NC_D + c);
      int s1 = __builtin_amdgcn_readlane(bdm, i * NC_D + c + 1);
      if (node0 + i < n) acc[i] = gather_run32(s0, s1, pairs, y1, j, half, acc[i]);
    }
  }
#pragma unroll
  for (int c = 0; c < NC_A; c++) {
#pragma unroll
    for (int i = 0; i < 8; i++) {
      int s0 = __builtin_amdgcn_readlane(bam, i * NC_A + c);
      int s1 = __builtin_amdgcn_readlane(bam, i * NC_A + c + 1);
      if (node0 + i < n) acc[i] = gather_run32(s0, s1, pairs, y2, j, half, acc[i]);
    }
  }
#pragma unroll
  for (int i = 0; i < 8; i++) {
    int node = node0 + i;
    if (node >= n) continue;
    float o = acc[i] + __shfl_xor(acc[i], 32);
    if (lane < 32) out[(size_t)node * 32 + lane] += o;
  }
}

static inline int nblkA(long long e) { return (int)((e + T_A - 1) / T_A); }

extern "C" void kernel_launch(void* const* d_in, const int* in_sizes, int n_in,
                              void* d_out, int out_size, void* d_ws, size_t ws_size,
                              hipStream_t stream) {
  const float* x_m = (const float*)d_in[0];
  const float* x_d = (const float*)d_in[1];
  const float* x_a = (const float*)d_in[2];
  const int* src_md = (const int*)d_in[3];
  const int* dst_md = (const int*)d_in[4];
  const float* ew_md = (const float*)d_in[5];
  const int* src_dm = (const int*)d_in[6];
  const int* dst_dm = (const int*)d_in[7];
  const float* ew_dm = (const float*)d_in[8];
  const int* src_ma = (const int*)d_in[9];
  const int* dst_ma = (const int*)d_in[10];
  const float* ew_ma = (const float*)d_in[11];
  const int* src_am = (const int*)d_in[12];
  const int* dst_am = (const int*)d_in[13];
  const float* ew_am = (const float*)d_in[14];
  const float* W1_rel = (const float*)d_in[15];
  const float* b1 = (const float*)d_in[16];
  const float* W1_root = (const float*)d_in[17];
  const float* W2_rel = (const float*)d_in[18];
  const float* b2 = (const float*)d_in[19];
  const float* W2_root = (const float*)d_in[20];

  const int E_md = in_sizes[3];
  const int E_dm = in_sizes[6];
  const int E_ma = in_sizes[9];
  const int E_am = in_sizes[12];
  const long long E_tot = (long long)E_md + E_dm + E_ma + E_am;

  // ---- workspace ----
  char* w = (char*)d_ws;
  u64* tmp = (u64*)w;       w += (size_t)E_tot * 8;
  u32* pairs = (u32*)w;     w += (size_t)E_tot * 4;
  int* bins = (int*)w;      w += (size_t)(B_TOT + 1) * 4;
  int* bucketHist = (int*)w; w += 512 * 4;
  int* bucketBase = (int*)w; w += (NBUCK + 1) * 4;
  int* cursor = (int*)w;     w += 512 * 4;
  u16* r_d  = (u16*)w;      w += (size_t)N_D * 64 * 2;
  u16* r_a  = (u16*)w;      w += (size_t)N_A * 64 * 2;
  u16* y_md = (u16*)w;      w += (size_t)N_M * 32 * 2;
  u16* y_dm = (u16*)w;      w += (size_t)N_D * 32 * 2;
  u16* y_ma = (u16*)w;      w += (size_t)N_M * 32 * 2;
  u16* y_am = (u16*)w;      w += (size_t)N_A * 32 * 2;
  if ((size_t)(w - (char*)d_ws) > ws_size) return;
  // tables aliasing tmp (written only after phaseB has consumed tmp)
  char* ta = (char*)tmp;
  u16* t_md = (u16*)ta;     ta += (size_t)N_M * 64 * 2;
  u16* t_dm = (u16*)ta;     ta += (size_t)N_D * 64 * 2;
  u16* t_ma = (u16*)ta;     ta += (size_t)N_M * 64 * 2;
  u16* t_am = (u16*)ta;     ta += (size_t)N_A * 64 * 2;
  u16* r_m  = (u16*)ta;     ta += (size_t)N_M * 64 * 2;

  float* o_m = (float*)d_out;
  float* o_d = o_m + (size_t)N_M * 32;
  float* o_a = o_d + (size_t)N_D * 32;

  // ---- bin build: 2-level counting sort ----
  hipMemsetAsync(bucketHist, 0, 512 * 4, stream);

  Rel4 P;
  P.r[0] = { src_md, dst_md, ew_md, E_md, BO_MD, NC_M };
  P.r[1] = { src_dm, dst_dm, ew_dm, E_dm, BO_DM, NC_D };
  P.r[2] = { src_ma, dst_ma, ew_ma, E_ma, BO_MA, NC_M };
  P.r[3] = { src_am, dst_am, ew_am, E_am, BO_AM, NC_A };
  P.blkStart[0] = 0;
  P.blkStart[1] = P.blkStart[0] + nblkA(E_md);
  P.blkStart[2] = P.blkStart[1] + nblkA(E_dm);
  P.blkStart[3] = P.blkStart[2] + nblkA(E_ma);
  P.blkStart[4] = P.blkStart[3] + nblkA(E_am);

  phase0<<<P.blkStart[4], 256, 0, stream>>>(P, bucketHist);
  scan_bucket<<<1, 256, 0, stream>>>(bucketHist, bucketBase, cursor);
  phaseA<<<P.blkStart[4], 256, 0, stream>>>(P, cursor, tmp);
  phaseB<<<NBUCK, 256, 0, stream>>>(tmp, bucketBase, pairs, bins);

  // ---- layer-1 dense transforms (write into tmp-aliased tables) ----
  l1_tr_m<<<768, 256, 0, stream>>>(x_m, W1_rel + 0 * 4096, W1_rel + 2 * 4096,
                                   W1_root + 1 * 4096, W1_root + 3 * 4096,
                                   b1 + 1 * 64, b1 + 3 * 64, t_md, t_ma, r_m, N_M);
  l1_tr_s<<<512, 256, 0, stream>>>(x_d, W1_rel + 1 * 4096, W1_root + 0 * 4096,
                                   b1 + 0 * 64, t_dm, r_d, N_D);
  l1_tr_s<<<512, 256, 0, stream>>>(x_a, W1_rel + 3 * 4096, W1_root + 2 * 4096,
                                   b1 + 2 * 64, t_am, r_a, N_A);

  // ---- fused L1-gather + L2-transform (writes root part to d_out) ----
  fused1<<<(N_D + 31) / 32, 256, 0, stream>>>(bins, pairs, t_md, r_d,
      W2_rel + 1 * 2048, W2_root + 0 * 2048, b2 + 0 * 32, y_dm, o_d, N_D, NC_M, BO_MD);
  fused1<<<(N_A + 31) / 32, 256, 0, stream>>>(bins, pairs, t_ma, r_a,
      W2_rel + 3 * 2048, W2_root + 2 * 2048, b2 + 2 * 32, y_am, o_a, N_A, NC_M, BO_MA);
  fusedm<<<(N_M + 31) / 32, 256, 0, stream>>>(bins, pairs, t_dm, t_am, r_m,
      W2_rel + 0 * 2048, W2_rel + 2 * 2048, W2_root + 1 * 2048, W2_root + 3 * 2048,
      b2 + 1 * 32, b2 + 3 * 32, y_md, y_ma, o_m, N_M);

  // ---- layer-2 gather, accumulate into d_out ----
  out1<<<(N_D + 31) / 32, 256, 0, stream>>>(bins, pairs, y_md, o_d, N_D, NC_M, BO_MD);
  out1<<<(N_A + 31) / 32, 256, 0, stream>>>(bins, pairs, y_ma, o_a, N_A, NC_M, BO_MA);
  outm<<<(N_M + 31) / 32, 256, 0, stream>>>(bins, pairs, y_dm, y_am, o_m, N_M);
}